// Round 1
// baseline (930.079 us; speedup 1.0000x reference)
//
#include <hip/hip_runtime.h>
#include <hip/hip_bf16.h>
#include <math.h>

#define N_NODES 200000
#define EMB_DIM 64
#define E_ADJ 1600000
#define E_TR 65536
#define NUM_NEG 16
#define NUM_LAYERS 3
#define EPS 1e-7f
#define MIN_NORM 1e-15f
#define MAX_SQDIST 50.0f
#define MARGIN 0.1f

__device__ __forceinline__ float wave_reduce_sum(float v) {
    #pragma unroll
    for (int off = 32; off > 0; off >>= 1)
        v += __shfl_xor(v, off, 64);
    return v;
}

// Kernel 1: row_ptr[r] = lower_bound(adj_row, r); also zero the scalar output.
__global__ void rowptr_kernel(const int* __restrict__ rows, int* __restrict__ rp,
                              float* __restrict__ out) {
    int r = blockIdx.x * blockDim.x + threadIdx.x;
    if (r == 0) out[0] = 0.0f;
    if (r > N_NODES) return;
    int lo = 0, hi = E_ADJ;
    while (lo < hi) {
        int mid = (lo + hi) >> 1;
        if (rows[mid] < r) lo = mid + 1; else hi = mid;
    }
    rp[r] = lo;
}

// Kernel 2: x_t = logmap0(weight, c=1). One wave per node, lane = dim.
__global__ void logmap0_kernel(const float* __restrict__ w, float* __restrict__ out) {
    int wave = (blockIdx.x * blockDim.x + threadIdx.x) >> 6;
    int lane = threadIdx.x & 63;
    if (wave >= N_NODES) return;
    float v = w[(size_t)wave * EMB_DIM + lane];
    float y = (lane == 0) ? 0.0f : v;
    float n2 = wave_reduce_sum(y * y);
    float ynorm = fmaxf(sqrtf(n2), MIN_NORM);
    float w0 = __shfl(v, 0, 64);
    float theta = fmaxf(w0, 1.0f + EPS);
    float scale = acoshf(theta) / ynorm;
    out[(size_t)wave * EMB_DIM + lane] = (lane == 0) ? 0.0f : scale * v;
}

// Kernel 3: one SpMM layer + accumulate. One wave per row, lane = dim.
__global__ void spmm_kernel(const float* __restrict__ h_in, float* __restrict__ h_out,
                            float* __restrict__ acc, const float* __restrict__ vals,
                            const int* __restrict__ cols, const int* __restrict__ rp,
                            int first) {
    int wave = (blockIdx.x * blockDim.x + threadIdx.x) >> 6;
    int lane = threadIdx.x & 63;
    if (wave >= N_NODES) return;
    int s = rp[wave], e = rp[wave + 1];
    float a = 0.0f;
    for (int i = s; i < e; ++i) {
        float v = vals[i];
        int c = cols[i];
        a = fmaf(v, h_in[(size_t)c * EMB_DIM + lane], a);
    }
    size_t o = (size_t)wave * EMB_DIM + lane;
    h_out[o] = a;
    if (first) acc[o] = a;
    else       acc[o] += a;
}

// Kernel 4: h = proj(expmap0(acc, c), c). One wave per node.
__global__ void expmap_proj_kernel(const float* __restrict__ acc, float* __restrict__ h) {
    int wave = (blockIdx.x * blockDim.x + threadIdx.x) >> 6;
    int lane = threadIdx.x & 63;
    if (wave >= N_NODES) return;
    float u = acc[(size_t)wave * EMB_DIM + lane];
    float x = (lane == 0) ? 0.0f : u;
    float n2 = wave_reduce_sum(x * x);
    float xn = fmaxf(sqrtf(n2), MIN_NORM);
    float sh = sinhf(xn);
    float rest = (lane == 0) ? 0.0f : sh * x / xn;
    float r2 = wave_reduce_sum(rest * rest);
    float first = sqrtf(1.0f + r2);
    h[(size_t)wave * EMB_DIM + lane] = (lane == 0) ? first : rest;
}

// Kernel 5: triplet loss with hard-negative mining. One wave per training edge.
__global__ void loss_kernel(const float* __restrict__ h, const int* __restrict__ anchor,
                            const int* __restrict__ pos, const int* __restrict__ neg,
                            float* __restrict__ out) {
    int wib = threadIdx.x >> 6;
    int lane = threadIdx.x & 63;
    int i = blockIdx.x * (blockDim.x >> 6) + wib;
    float loss = 0.0f;
    if (i < E_TR) {
        const float* A = h + (size_t)anchor[i] * EMB_DIM;
        const float* P = h + (size_t)pos[i] * EMB_DIM;
        float a = A[lane];
        float p = P[lane];
        float dot_ap = wave_reduce_sum(a * p);
        float a0 = __shfl(a, 0, 64);
        float p0 = __shfl(p, 0, 64);
        float mink = dot_ap - 2.0f * a0 * p0;
        float th = fmaxf(-mink, 1.0f + EPS);
        float ac = acoshf(th);
        float pos_score = fminf(ac * ac, MAX_SQDIST);
        float score = (1.0f - mink - a0 - p0) / (a0 * p0);
        float w = 1.0f / (1.0f + expf(score));   // sigmoid(-score)

        float best_d2 = 3.4e38f, best_dot = 0.0f, best_n0 = 1.0f;
        #pragma unroll 4
        for (int j = 0; j < NUM_NEG; ++j) {
            const float* Nv = h + (size_t)neg[(size_t)i * NUM_NEG + j] * EMB_DIM;
            float nv = Nv[lane];
            float d = nv - p;
            float s1 = d * d;
            float s2 = a * nv;
            #pragma unroll
            for (int off = 32; off > 0; off >>= 1) {
                s1 += __shfl_xor(s1, off, 64);
                s2 += __shfl_xor(s2, off, 64);
            }
            float n0 = __shfl(nv, 0, 64);
            if (s1 < best_d2) { best_d2 = s1; best_dot = s2; best_n0 = n0; }
        }
        float minkn = best_dot - 2.0f * a0 * best_n0;
        float thn = fmaxf(-minkn, 1.0f + EPS);
        float acn = acoshf(thn);
        float neg_score = fminf(acn * acn, MAX_SQDIST);
        loss = fmaxf(pos_score - neg_score + MARGIN * w, 0.0f);
    }
    __shared__ float part[4];
    if (lane == 0) part[wib] = loss;
    __syncthreads();
    if (threadIdx.x == 0) {
        atomicAdd(out, part[0] + part[1] + part[2] + part[3]);
    }
}

extern "C" void kernel_launch(void* const* d_in, const int* in_sizes, int n_in,
                              void* d_out, int out_size, void* d_ws, size_t ws_size,
                              hipStream_t stream) {
    const float* weight   = (const float*)d_in[0];
    const float* adj_vals = (const float*)d_in[1];
    const int*   adj_row  = (const int*)d_in[2];
    const int*   adj_col  = (const int*)d_in[3];
    const int*   anchor   = (const int*)d_in[4];
    const int*   pos      = (const int*)d_in[5];
    const int*   neg      = (const int*)d_in[6];
    float* out = (float*)d_out;

    const size_t NODE_BYTES = (size_t)N_NODES * EMB_DIM * sizeof(float); // 51.2 MB
    char* ws = (char*)d_ws;
    float* buf0 = (float*)(ws);                    // x_t / h ping / final h
    float* buf1 = (float*)(ws + NODE_BYTES);       // h pong
    float* accb = (float*)(ws + 2 * NODE_BYTES);   // accumulated layers
    int*   rp   = (int*)(ws + 3 * NODE_BYTES);     // row_ptr[N_NODES+1]

    // 1. row_ptr + zero output
    {
        int nth = N_NODES + 1;
        rowptr_kernel<<<(nth + 255) / 256, 256, 0, stream>>>(adj_row, rp, out);
    }
    // 2. logmap0 -> buf0
    {
        int nblk = (N_NODES + 3) / 4;  // 4 waves per 256-thread block
        logmap0_kernel<<<nblk, 256, 0, stream>>>(weight, buf0);
    }
    // 3. three SpMM layers, accumulating into accb
    {
        int nblk = (N_NODES + 3) / 4;
        spmm_kernel<<<nblk, 256, 0, stream>>>(buf0, buf1, accb, adj_vals, adj_col, rp, 1);
        spmm_kernel<<<nblk, 256, 0, stream>>>(buf1, buf0, accb, adj_vals, adj_col, rp, 0);
        spmm_kernel<<<nblk, 256, 0, stream>>>(buf0, buf1, accb, adj_vals, adj_col, rp, 0);
    }
    // 4. expmap0 + proj -> buf0 (final embeddings)
    {
        int nblk = (N_NODES + 3) / 4;
        expmap_proj_kernel<<<nblk, 256, 0, stream>>>(accb, buf0);
    }
    // 5. loss
    {
        int nblk = E_TR / 4;  // 4 waves (training edges) per block
        loss_kernel<<<nblk, 256, 0, stream>>>(buf0, anchor, pos, neg, out);
    }
}

// Round 2
// 666.808 us; speedup vs baseline: 1.3948x; 1.3948x over previous
//
#include <hip/hip_runtime.h>
#include <hip/hip_bf16.h>
#include <math.h>

#define N_NODES 200000
#define EMB_DIM 64
#define E_ADJ 1600000
#define E_TR 65536
#define NUM_NEG 16
#define EPS 1e-7f
#define MIN_NORM 1e-15f
#define MAX_SQDIST 50.0f
#define MARGIN 0.1f

__device__ __forceinline__ float wave_reduce_sum(float v) {
    #pragma unroll
    for (int off = 32; off > 0; off >>= 1)
        v += __shfl_xor(v, off, 64);
    return v;
}

// Kernel 1: row_ptr[r] = lower_bound(adj_row, r); also zero the scalar output.
__global__ void rowptr_kernel(const int* __restrict__ rows, int* __restrict__ rp,
                              float* __restrict__ out) {
    int r = blockIdx.x * blockDim.x + threadIdx.x;
    if (r == 0) out[0] = 0.0f;
    if (r > N_NODES) return;
    int lo = 0, hi = E_ADJ;
    while (lo < hi) {
        int mid = (lo + hi) >> 1;
        if (rows[mid] < r) lo = mid + 1; else hi = mid;
    }
    rp[r] = lo;
}

// Kernel 2: x_t = logmap0(weight, c=1). One wave per node, lane = dim.
__global__ void logmap0_kernel(const float* __restrict__ w, float* __restrict__ out) {
    int wave = (blockIdx.x * blockDim.x + threadIdx.x) >> 6;
    int lane = threadIdx.x & 63;
    if (wave >= N_NODES) return;
    float v = w[(size_t)wave * EMB_DIM + lane];
    float y = (lane == 0) ? 0.0f : v;
    float n2 = wave_reduce_sum(y * y);
    float ynorm = fmaxf(sqrtf(n2), MIN_NORM);
    float w0 = __shfl(v, 0, 64);
    float theta = fmaxf(w0, 1.0f + EPS);
    float scale = acoshf(theta) / ynorm;
    out[(size_t)wave * EMB_DIM + lane] = (lane == 0) ? 0.0f : scale * v;
}

// Kernel 3: one SpMM layer. One wave per row, lane = dim. Edge loop batched x8
// so gathers issue in flight before the fma chain consumes them.
__global__ void spmm_kernel(const float* __restrict__ h_in, float* __restrict__ h_out,
                            const float* __restrict__ vals, const int* __restrict__ cols,
                            const int* __restrict__ rp) {
    int row = (blockIdx.x * blockDim.x + threadIdx.x) >> 6;
    int lane = threadIdx.x & 63;
    if (row >= N_NODES) return;
    int s = rp[row], e = rp[row + 1];
    float a = 0.0f;
    int i = s;
    for (; i + 8 <= e; i += 8) {
        int c0 = cols[i + 0], c1 = cols[i + 1], c2 = cols[i + 2], c3 = cols[i + 3];
        int c4 = cols[i + 4], c5 = cols[i + 5], c6 = cols[i + 6], c7 = cols[i + 7];
        float v0 = vals[i + 0], v1 = vals[i + 1], v2 = vals[i + 2], v3 = vals[i + 3];
        float v4 = vals[i + 4], v5 = vals[i + 5], v6 = vals[i + 6], v7 = vals[i + 7];
        float g0 = h_in[(size_t)c0 * EMB_DIM + lane];
        float g1 = h_in[(size_t)c1 * EMB_DIM + lane];
        float g2 = h_in[(size_t)c2 * EMB_DIM + lane];
        float g3 = h_in[(size_t)c3 * EMB_DIM + lane];
        float g4 = h_in[(size_t)c4 * EMB_DIM + lane];
        float g5 = h_in[(size_t)c5 * EMB_DIM + lane];
        float g6 = h_in[(size_t)c6 * EMB_DIM + lane];
        float g7 = h_in[(size_t)c7 * EMB_DIM + lane];
        a = fmaf(v0, g0, a); a = fmaf(v1, g1, a);
        a = fmaf(v2, g2, a); a = fmaf(v3, g3, a);
        a = fmaf(v4, g4, a); a = fmaf(v5, g5, a);
        a = fmaf(v6, g6, a); a = fmaf(v7, g7, a);
    }
    for (; i + 4 <= e; i += 4) {
        int c0 = cols[i + 0], c1 = cols[i + 1], c2 = cols[i + 2], c3 = cols[i + 3];
        float v0 = vals[i + 0], v1 = vals[i + 1], v2 = vals[i + 2], v3 = vals[i + 3];
        float g0 = h_in[(size_t)c0 * EMB_DIM + lane];
        float g1 = h_in[(size_t)c1 * EMB_DIM + lane];
        float g2 = h_in[(size_t)c2 * EMB_DIM + lane];
        float g3 = h_in[(size_t)c3 * EMB_DIM + lane];
        a = fmaf(v0, g0, a); a = fmaf(v1, g1, a);
        a = fmaf(v2, g2, a); a = fmaf(v3, g3, a);
    }
    for (; i < e; ++i)
        a = fmaf(vals[i], h_in[(size_t)cols[i] * EMB_DIM + lane], a);
    h_out[(size_t)row * EMB_DIM + lane] = a;
}

// Kernel 4: h = proj(expmap0(h1+h2+h3, c), c). Also emits per-node ||h||^2.
__global__ void expmap_proj_kernel(const float* __restrict__ h1, const float* __restrict__ h2,
                                   const float* __restrict__ h3, float* __restrict__ h,
                                   float* __restrict__ nrm2) {
    int wave = (blockIdx.x * blockDim.x + threadIdx.x) >> 6;
    int lane = threadIdx.x & 63;
    if (wave >= N_NODES) return;
    size_t o = (size_t)wave * EMB_DIM + lane;
    float u = (h1[o] + h2[o]) + h3[o];     // match ref accumulate order
    float x = (lane == 0) ? 0.0f : u;
    float n2 = wave_reduce_sum(x * x);
    float xn = fmaxf(sqrtf(n2), MIN_NORM);
    float sh = sinhf(xn);
    float rest = (lane == 0) ? 0.0f : sh * x / xn;
    float r2 = wave_reduce_sum(rest * rest);
    float first = sqrtf(1.0f + r2);
    h[o] = (lane == 0) ? first : rest;
    if (lane == 0) nrm2[wave] = first * first + r2;  // ||h||^2
}

// Kernel 5: triplet loss with hard-negative mining. One wave per training edge.
// All 16 neg gathers issued upfront; d2 via precomputed norms -> 1 reduction/neg.
__global__ void loss_kernel(const float* __restrict__ h, const float* __restrict__ nrm2,
                            const int* __restrict__ anchor, const int* __restrict__ pos,
                            const int* __restrict__ neg, float* __restrict__ out) {
    int wib = threadIdx.x >> 6;
    int lane = threadIdx.x & 63;
    int i = blockIdx.x * (blockDim.x >> 6) + wib;
    float loss = 0.0f;
    if (i < E_TR) {
        int ia = anchor[i], ip = pos[i];
        float a = h[(size_t)ia * EMB_DIM + lane];
        float p = h[(size_t)ip * EMB_DIM + lane];

        int nidx[NUM_NEG];
        const int* nrow = neg + (size_t)i * NUM_NEG;
        #pragma unroll
        for (int j = 0; j < NUM_NEG; ++j) nidx[j] = nrow[j];

        float s[NUM_NEG];
        #pragma unroll
        for (int j = 0; j < NUM_NEG; ++j)
            s[j] = p * h[(size_t)nidx[j] * EMB_DIM + lane];   // 16 gathers in flight

        float dap = wave_reduce_sum(a * p);
        #pragma unroll
        for (int j = 0; j < NUM_NEG; ++j)
            s[j] = wave_reduce_sum(s[j]);                     // independent butterflies

        float np2 = nrm2[ip];
        float best = 3.4e38f;
        int bj = 0;
        #pragma unroll
        for (int j = 0; j < NUM_NEG; ++j) {
            float d2 = nrm2[nidx[j]] + np2 - 2.0f * s[j];
            if (d2 < best) { best = d2; bj = j; }             // uniform across lanes
        }
        int iw = nidx[bj];
        float nw = h[(size_t)iw * EMB_DIM + lane];
        float dan = wave_reduce_sum(a * nw);

        float a0 = __shfl(a, 0, 64);
        float p0 = __shfl(p, 0, 64);
        float n0 = __shfl(nw, 0, 64);
        float mink = dap - 2.0f * a0 * p0;
        float th = fmaxf(-mink, 1.0f + EPS);
        float ac = acoshf(th);
        float pos_score = fminf(ac * ac, MAX_SQDIST);
        float score = (1.0f - mink - a0 - p0) / (a0 * p0);
        float w = 1.0f / (1.0f + expf(score));                // sigmoid(-score)
        float minkn = dan - 2.0f * a0 * n0;
        float thn = fmaxf(-minkn, 1.0f + EPS);
        float acn = acoshf(thn);
        float neg_score = fminf(acn * acn, MAX_SQDIST);
        loss = fmaxf(pos_score - neg_score + MARGIN * w, 0.0f);
    }
    __shared__ float part[4];
    if (lane == 0) part[wib] = loss;
    __syncthreads();
    if (threadIdx.x == 0)
        atomicAdd(out, part[0] + part[1] + part[2] + part[3]);
}

extern "C" void kernel_launch(void* const* d_in, const int* in_sizes, int n_in,
                              void* d_out, int out_size, void* d_ws, size_t ws_size,
                              hipStream_t stream) {
    const float* weight   = (const float*)d_in[0];
    const float* adj_vals = (const float*)d_in[1];
    const int*   adj_row  = (const int*)d_in[2];
    const int*   adj_col  = (const int*)d_in[3];
    const int*   anchor   = (const int*)d_in[4];
    const int*   pos      = (const int*)d_in[5];
    const int*   neg      = (const int*)d_in[6];
    float* out = (float*)d_out;

    const size_t NODE_BYTES = (size_t)N_NODES * EMB_DIM * sizeof(float); // 51.2 MB
    char* ws = (char*)d_ws;
    float* buf0 = (float*)(ws);                    // x_t, later h3
    float* buf1 = (float*)(ws + NODE_BYTES);       // h1, later final h
    float* buf2 = (float*)(ws + 2 * NODE_BYTES);   // h2
    int*   rp   = (int*)(ws + 3 * NODE_BYTES);                 // row_ptr[N_NODES+1]
    float* nrm2 = (float*)(ws + 3 * NODE_BYTES + ((size_t)(N_NODES + 2) * 4)); // ||h||^2

    int nblk = (N_NODES + 3) / 4;  // 4 waves per 256-thread block

    // 1. row_ptr + zero output
    rowptr_kernel<<<(N_NODES + 1 + 255) / 256, 256, 0, stream>>>(adj_row, rp, out);
    // 2. logmap0 -> buf0
    logmap0_kernel<<<nblk, 256, 0, stream>>>(weight, buf0);
    // 3. three SpMM layers: x_t->h1->h2->h3 (h3 overwrites dead x_t)
    spmm_kernel<<<nblk, 256, 0, stream>>>(buf0, buf1, adj_vals, adj_col, rp);
    spmm_kernel<<<nblk, 256, 0, stream>>>(buf1, buf2, adj_vals, adj_col, rp);
    spmm_kernel<<<nblk, 256, 0, stream>>>(buf2, buf0, adj_vals, adj_col, rp);
    // 4. expmap0 + proj: sum(h1,h2,h3) -> final h in buf1... but buf1 is an input.
    //    Write final h into a region not aliasing h1/h2/h3 inputs: reuse is unsafe,
    //    so stage final h + norms after rp/nrm2 region? Simpler: final h -> buf1 is
    //    aliased. Use dedicated slice: place final h at ws + 3*NODE_BYTES + 2MB.
    {
        float* hfin = (float*)(ws + 3 * NODE_BYTES + (size_t)(2 * 1024 * 1024));
        expmap_proj_kernel<<<nblk, 256, 0, stream>>>(buf1, buf2, buf0, hfin, nrm2);
        // 5. loss
        loss_kernel<<<E_TR / 4, 256, 0, stream>>>(hfin, nrm2, anchor, pos, neg, out);
    }
}

// Round 3
// 541.327 us; speedup vs baseline: 1.7181x; 1.2318x over previous
//
#include <hip/hip_runtime.h>
#include <hip/hip_bf16.h>
#include <math.h>

#define N_NODES 200000
#define EMB_DIM 64
#define E_ADJ 1600000
#define E_TR 65536
#define NUM_NEG 16
#define EPS 1e-7f
#define MIN_NORM 1e-15f
#define MAX_SQDIST 50.0f
#define MARGIN 0.1f
#define LOSS_BLOCKS (E_TR / 4)   // 16384 blocks, 4 edges (waves) each

__device__ __forceinline__ float wave_reduce_sum(float v) {
    #pragma unroll
    for (int off = 32; off > 0; off >>= 1)
        v += __shfl_xor(v, off, 64);
    return v;
}

// Kernel 1: row_ptr[r] = lower_bound(adj_row, r).
__global__ void rowptr_kernel(const int* __restrict__ rows, int* __restrict__ rp) {
    int r = blockIdx.x * blockDim.x + threadIdx.x;
    if (r > N_NODES) return;
    int lo = 0, hi = E_ADJ;
    while (lo < hi) {
        int mid = (lo + hi) >> 1;
        if (rows[mid] < r) lo = mid + 1; else hi = mid;
    }
    rp[r] = lo;
}

// Kernel 2: x_t = logmap0(weight, c=1). One wave per node, lane = dim.
__global__ void logmap0_kernel(const float* __restrict__ w, float* __restrict__ out) {
    int wave = (blockIdx.x * blockDim.x + threadIdx.x) >> 6;
    int lane = threadIdx.x & 63;
    if (wave >= N_NODES) return;
    float v = w[(size_t)wave * EMB_DIM + lane];
    float y = (lane == 0) ? 0.0f : v;
    float n2 = wave_reduce_sum(y * y);
    float ynorm = fmaxf(sqrtf(n2), MIN_NORM);
    float w0 = __shfl(v, 0, 64);
    float theta = fmaxf(w0, 1.0f + EPS);
    float scale = acoshf(theta) / ynorm;
    out[(size_t)wave * EMB_DIM + lane] = (lane == 0) ? 0.0f : scale * v;
}

// Kernel 3: one SpMM layer. One wave per row, lane = dim. Edge loop batched x8.
__global__ void spmm_kernel(const float* __restrict__ h_in, float* __restrict__ h_out,
                            const float* __restrict__ vals, const int* __restrict__ cols,
                            const int* __restrict__ rp) {
    int row = (blockIdx.x * blockDim.x + threadIdx.x) >> 6;
    int lane = threadIdx.x & 63;
    if (row >= N_NODES) return;
    int s = rp[row], e = rp[row + 1];
    float a = 0.0f;
    int i = s;
    for (; i + 8 <= e; i += 8) {
        int c0 = cols[i + 0], c1 = cols[i + 1], c2 = cols[i + 2], c3 = cols[i + 3];
        int c4 = cols[i + 4], c5 = cols[i + 5], c6 = cols[i + 6], c7 = cols[i + 7];
        float v0 = vals[i + 0], v1 = vals[i + 1], v2 = vals[i + 2], v3 = vals[i + 3];
        float v4 = vals[i + 4], v5 = vals[i + 5], v6 = vals[i + 6], v7 = vals[i + 7];
        float g0 = h_in[(size_t)c0 * EMB_DIM + lane];
        float g1 = h_in[(size_t)c1 * EMB_DIM + lane];
        float g2 = h_in[(size_t)c2 * EMB_DIM + lane];
        float g3 = h_in[(size_t)c3 * EMB_DIM + lane];
        float g4 = h_in[(size_t)c4 * EMB_DIM + lane];
        float g5 = h_in[(size_t)c5 * EMB_DIM + lane];
        float g6 = h_in[(size_t)c6 * EMB_DIM + lane];
        float g7 = h_in[(size_t)c7 * EMB_DIM + lane];
        a = fmaf(v0, g0, a); a = fmaf(v1, g1, a);
        a = fmaf(v2, g2, a); a = fmaf(v3, g3, a);
        a = fmaf(v4, g4, a); a = fmaf(v5, g5, a);
        a = fmaf(v6, g6, a); a = fmaf(v7, g7, a);
    }
    for (; i + 4 <= e; i += 4) {
        int c0 = cols[i + 0], c1 = cols[i + 1], c2 = cols[i + 2], c3 = cols[i + 3];
        float v0 = vals[i + 0], v1 = vals[i + 1], v2 = vals[i + 2], v3 = vals[i + 3];
        float g0 = h_in[(size_t)c0 * EMB_DIM + lane];
        float g1 = h_in[(size_t)c1 * EMB_DIM + lane];
        float g2 = h_in[(size_t)c2 * EMB_DIM + lane];
        float g3 = h_in[(size_t)c3 * EMB_DIM + lane];
        a = fmaf(v0, g0, a); a = fmaf(v1, g1, a);
        a = fmaf(v2, g2, a); a = fmaf(v3, g3, a);
    }
    for (; i < e; ++i)
        a = fmaf(vals[i], h_in[(size_t)cols[i] * EMB_DIM + lane], a);
    h_out[(size_t)row * EMB_DIM + lane] = a;
}

// Kernel 4: h = proj(expmap0(h1+h2+h3, c), c). Also emits per-node ||h||^2.
__global__ void expmap_proj_kernel(const float* __restrict__ h1, const float* __restrict__ h2,
                                   const float* __restrict__ h3, float* __restrict__ h,
                                   float* __restrict__ nrm2) {
    int wave = (blockIdx.x * blockDim.x + threadIdx.x) >> 6;
    int lane = threadIdx.x & 63;
    if (wave >= N_NODES) return;
    size_t o = (size_t)wave * EMB_DIM + lane;
    float u = (h1[o] + h2[o]) + h3[o];     // match ref accumulate order
    float x = (lane == 0) ? 0.0f : u;
    float n2 = wave_reduce_sum(x * x);
    float xn = fmaxf(sqrtf(n2), MIN_NORM);
    float sh = sinhf(xn);
    float rest = (lane == 0) ? 0.0f : sh * x / xn;
    float r2 = wave_reduce_sum(rest * rest);
    float first = sqrtf(1.0f + r2);
    h[o] = (lane == 0) ? first : rest;
    if (lane == 0) nrm2[wave] = first * first + r2;  // ||h||^2
}

// Kernel 5: triplet loss with hard-negative mining. One wave per training edge.
// No atomics: each block writes one partial, coalesced, zero contention.
__global__ void loss_kernel(const float* __restrict__ h, const float* __restrict__ nrm2,
                            const int* __restrict__ anchor, const int* __restrict__ pos,
                            const int* __restrict__ neg, float* __restrict__ partials) {
    int wib = threadIdx.x >> 6;
    int lane = threadIdx.x & 63;
    int i = blockIdx.x * (blockDim.x >> 6) + wib;
    float loss = 0.0f;
    if (i < E_TR) {
        int ia = anchor[i], ip = pos[i];
        float a = h[(size_t)ia * EMB_DIM + lane];
        float p = h[(size_t)ip * EMB_DIM + lane];

        int nidx[NUM_NEG];
        const int* nrow = neg + (size_t)i * NUM_NEG;
        #pragma unroll
        for (int j = 0; j < NUM_NEG; ++j) nidx[j] = nrow[j];

        float s[NUM_NEG];
        #pragma unroll
        for (int j = 0; j < NUM_NEG; ++j)
            s[j] = p * h[(size_t)nidx[j] * EMB_DIM + lane];   // 16 gathers in flight

        float dap = wave_reduce_sum(a * p);
        #pragma unroll
        for (int j = 0; j < NUM_NEG; ++j)
            s[j] = wave_reduce_sum(s[j]);                     // independent butterflies

        float np2 = nrm2[ip];
        float best = 3.4e38f;
        int bj = 0;
        #pragma unroll
        for (int j = 0; j < NUM_NEG; ++j) {
            float d2 = nrm2[nidx[j]] + np2 - 2.0f * s[j];
            if (d2 < best) { best = d2; bj = j; }             // uniform across lanes
        }
        int iw = nidx[bj];
        float nw = h[(size_t)iw * EMB_DIM + lane];
        float dan = wave_reduce_sum(a * nw);

        float a0 = __shfl(a, 0, 64);
        float p0 = __shfl(p, 0, 64);
        float n0 = __shfl(nw, 0, 64);
        float mink = dap - 2.0f * a0 * p0;
        float th = fmaxf(-mink, 1.0f + EPS);
        float ac = acoshf(th);
        float pos_score = fminf(ac * ac, MAX_SQDIST);
        float score = (1.0f - mink - a0 - p0) / (a0 * p0);
        float w = 1.0f / (1.0f + expf(score));                // sigmoid(-score)
        float minkn = dan - 2.0f * a0 * n0;
        float thn = fmaxf(-minkn, 1.0f + EPS);
        float acn = acoshf(thn);
        float neg_score = fminf(acn * acn, MAX_SQDIST);
        loss = fmaxf(pos_score - neg_score + MARGIN * w, 0.0f);
    }
    __shared__ float part[4];
    if (lane == 0) part[wib] = loss;
    __syncthreads();
    if (threadIdx.x == 0)
        partials[blockIdx.x] = part[0] + part[1] + part[2] + part[3];
}

// Kernel 6: sum the per-block partials. Single block, 1024 threads.
__global__ void reduce_kernel(const float* __restrict__ partials, float* __restrict__ out) {
    int tid = threadIdx.x;
    float s = 0.0f;
    for (int i = tid; i < LOSS_BLOCKS; i += 1024)
        s += partials[i];
    s = wave_reduce_sum(s);
    __shared__ float part[16];
    if ((tid & 63) == 0) part[tid >> 6] = s;
    __syncthreads();
    if (tid == 0) {
        float t = 0.0f;
        #pragma unroll
        for (int k = 0; k < 16; ++k) t += part[k];
        out[0] = t;
    }
}

extern "C" void kernel_launch(void* const* d_in, const int* in_sizes, int n_in,
                              void* d_out, int out_size, void* d_ws, size_t ws_size,
                              hipStream_t stream) {
    const float* weight   = (const float*)d_in[0];
    const float* adj_vals = (const float*)d_in[1];
    const int*   adj_row  = (const int*)d_in[2];
    const int*   adj_col  = (const int*)d_in[3];
    const int*   anchor   = (const int*)d_in[4];
    const int*   pos      = (const int*)d_in[5];
    const int*   neg      = (const int*)d_in[6];
    float* out = (float*)d_out;

    const size_t NODE_BYTES = (size_t)N_NODES * EMB_DIM * sizeof(float); // 51.2 MB
    char* ws = (char*)d_ws;
    float* buf0 = (float*)(ws);                    // x_t, later h3
    float* buf1 = (float*)(ws + NODE_BYTES);       // h1
    float* buf2 = (float*)(ws + 2 * NODE_BYTES);   // h2
    int*   rp   = (int*)(ws + 3 * NODE_BYTES);                                  // row_ptr
    float* nrm2 = (float*)(ws + 3 * NODE_BYTES + ((size_t)(N_NODES + 2) * 4));  // ||h||^2
    float* hfin = (float*)(ws + 3 * NODE_BYTES + (size_t)(2 * 1024 * 1024));    // final h
    float* partials = (float*)(ws + 4 * NODE_BYTES + (size_t)(2 * 1024 * 1024)); // 64 KB

    int nblk = (N_NODES + 3) / 4;  // 4 waves per 256-thread block

    rowptr_kernel<<<(N_NODES + 1 + 255) / 256, 256, 0, stream>>>(adj_row, rp);
    logmap0_kernel<<<nblk, 256, 0, stream>>>(weight, buf0);
    spmm_kernel<<<nblk, 256, 0, stream>>>(buf0, buf1, adj_vals, adj_col, rp);
    spmm_kernel<<<nblk, 256, 0, stream>>>(buf1, buf2, adj_vals, adj_col, rp);
    spmm_kernel<<<nblk, 256, 0, stream>>>(buf2, buf0, adj_vals, adj_col, rp);
    expmap_proj_kernel<<<nblk, 256, 0, stream>>>(buf1, buf2, buf0, hfin, nrm2);
    loss_kernel<<<LOSS_BLOCKS, 256, 0, stream>>>(hfin, nrm2, anchor, pos, neg, partials);
    reduce_kernel<<<1, 1024, 0, stream>>>(partials, out);
}

// Round 4
// 429.608 us; speedup vs baseline: 2.1649x; 1.2600x over previous
//
#include <hip/hip_runtime.h>
#include <hip/hip_bf16.h>
#include <math.h>

#define N_NODES 200000
#define EMB_DIM 64
#define E_ADJ 1600000
#define E_TR 65536
#define NUM_NEG 16
#define EPS 1e-7f
#define MIN_NORM 1e-15f
#define MAX_SQDIST 50.0f
#define MARGIN 0.1f
#define LOSS_BLOCKS (E_TR / 4)   // 16384 blocks, 4 edges (waves) each

__device__ __forceinline__ float group_reduce16(float v) {
    // sum across the 16-lane group (lanes sharing lane>>4)
    v += __shfl_xor(v, 8, 64);
    v += __shfl_xor(v, 4, 64);
    v += __shfl_xor(v, 2, 64);
    v += __shfl_xor(v, 1, 64);
    return v;
}

__device__ __forceinline__ float dot4(float4 a, float4 b) {
    return a.x * b.x + a.y * b.y + a.z * b.z + a.w * b.w;
}

// Kernel 1: row_ptr[r] = lower_bound(adj_row, r).
__global__ void rowptr_kernel(const int* __restrict__ rows, int* __restrict__ rp) {
    int r = blockIdx.x * blockDim.x + threadIdx.x;
    if (r > N_NODES) return;
    int lo = 0, hi = E_ADJ;
    while (lo < hi) {
        int mid = (lo + hi) >> 1;
        if (rows[mid] < r) lo = mid + 1; else hi = mid;
    }
    rp[r] = lo;
}

// Kernel 2: x_t = logmap0(weight). Wave handles 4 nodes; 16-lane group per node.
__global__ void logmap0_kernel(const float* __restrict__ w, float* __restrict__ out) {
    int wave = (blockIdx.x * blockDim.x + threadIdx.x) >> 6;
    int lane = threadIdx.x & 63;
    int e = lane >> 4, d = lane & 15;
    int node = wave * 4 + e;
    if (node >= N_NODES) return;
    float4 v = ((const float4*)(w + (size_t)node * EMB_DIM))[d];
    float4 y = v;
    if (d == 0) y.x = 0.0f;
    float n2 = group_reduce16(dot4(y, y));
    float ynorm = fmaxf(sqrtf(n2), MIN_NORM);
    float w0 = __shfl(v.x, lane & 48, 64);      // broadcast d==0 lane of group
    float theta = fmaxf(w0, 1.0f + EPS);
    float scale = acoshf(theta) / ynorm;
    float4 o;
    o.x = scale * y.x; o.y = scale * y.y; o.z = scale * y.z; o.w = scale * y.w;
    ((float4*)(out + (size_t)node * EMB_DIM))[d] = o;
}

// Kernel 3: one SpMM layer. One wave per row; lane=16e+d; 4 edges per gather instr.
__global__ void spmm_kernel(const float* __restrict__ h_in, float* __restrict__ h_out,
                            const float* __restrict__ vals, const int* __restrict__ cols,
                            const int* __restrict__ rp) {
    int row = (blockIdx.x * blockDim.x + threadIdx.x) >> 6;
    int lane = threadIdx.x & 63;
    int e = lane >> 4, d = lane & 15;
    if (row >= N_NODES) return;
    int s = rp[row], eend = rp[row + 1];
    float4 acc = make_float4(0.f, 0.f, 0.f, 0.f);
    int i = s;
    for (; i + 8 <= eend; i += 8) {
        int   c0 = cols[i + e],     c1 = cols[i + 4 + e];
        float v0 = vals[i + e],     v1 = vals[i + 4 + e];
        float4 g0 = ((const float4*)(h_in + (size_t)c0 * EMB_DIM))[d];
        float4 g1 = ((const float4*)(h_in + (size_t)c1 * EMB_DIM))[d];
        acc.x = fmaf(v0, g0.x, acc.x); acc.y = fmaf(v0, g0.y, acc.y);
        acc.z = fmaf(v0, g0.z, acc.z); acc.w = fmaf(v0, g0.w, acc.w);
        acc.x = fmaf(v1, g1.x, acc.x); acc.y = fmaf(v1, g1.y, acc.y);
        acc.z = fmaf(v1, g1.z, acc.z); acc.w = fmaf(v1, g1.w, acc.w);
    }
    if (i + 4 <= eend) {
        int   c0 = cols[i + e];
        float v0 = vals[i + e];
        float4 g0 = ((const float4*)(h_in + (size_t)c0 * EMB_DIM))[d];
        acc.x = fmaf(v0, g0.x, acc.x); acc.y = fmaf(v0, g0.y, acc.y);
        acc.z = fmaf(v0, g0.z, acc.z); acc.w = fmaf(v0, g0.w, acc.w);
        i += 4;
    }
    if (i + e < eend) {
        int   c = cols[i + e];
        float v = vals[i + e];
        float4 g = ((const float4*)(h_in + (size_t)c * EMB_DIM))[d];
        acc.x = fmaf(v, g.x, acc.x); acc.y = fmaf(v, g.y, acc.y);
        acc.z = fmaf(v, g.z, acc.z); acc.w = fmaf(v, g.w, acc.w);
    }
    // sum across the 4 edge-slot groups (same d, different e)
    acc.x += __shfl_xor(acc.x, 16, 64); acc.y += __shfl_xor(acc.y, 16, 64);
    acc.z += __shfl_xor(acc.z, 16, 64); acc.w += __shfl_xor(acc.w, 16, 64);
    acc.x += __shfl_xor(acc.x, 32, 64); acc.y += __shfl_xor(acc.y, 32, 64);
    acc.z += __shfl_xor(acc.z, 32, 64); acc.w += __shfl_xor(acc.w, 32, 64);
    if (e == 0)
        ((float4*)(h_out + (size_t)row * EMB_DIM))[d] = acc;
}

// Kernel 4: fused layer-3 SpMM + (h1+h2+h3) + expmap0 + proj. Emits h and ||h||^2.
__global__ void spmm_expmap_kernel(const float* __restrict__ h_gather,  // h2 (gather src)
                                   const float* __restrict__ h1, const float* __restrict__ h2,
                                   float* __restrict__ h, float* __restrict__ nrm2,
                                   const float* __restrict__ vals, const int* __restrict__ cols,
                                   const int* __restrict__ rp) {
    int row = (blockIdx.x * blockDim.x + threadIdx.x) >> 6;
    int lane = threadIdx.x & 63;
    int e = lane >> 4, d = lane & 15;
    if (row >= N_NODES) return;
    int s = rp[row], eend = rp[row + 1];
    float4 acc = make_float4(0.f, 0.f, 0.f, 0.f);
    int i = s;
    for (; i + 8 <= eend; i += 8) {
        int   c0 = cols[i + e],     c1 = cols[i + 4 + e];
        float v0 = vals[i + e],     v1 = vals[i + 4 + e];
        float4 g0 = ((const float4*)(h_gather + (size_t)c0 * EMB_DIM))[d];
        float4 g1 = ((const float4*)(h_gather + (size_t)c1 * EMB_DIM))[d];
        acc.x = fmaf(v0, g0.x, acc.x); acc.y = fmaf(v0, g0.y, acc.y);
        acc.z = fmaf(v0, g0.z, acc.z); acc.w = fmaf(v0, g0.w, acc.w);
        acc.x = fmaf(v1, g1.x, acc.x); acc.y = fmaf(v1, g1.y, acc.y);
        acc.z = fmaf(v1, g1.z, acc.z); acc.w = fmaf(v1, g1.w, acc.w);
    }
    if (i + 4 <= eend) {
        int   c0 = cols[i + e];
        float v0 = vals[i + e];
        float4 g0 = ((const float4*)(h_gather + (size_t)c0 * EMB_DIM))[d];
        acc.x = fmaf(v0, g0.x, acc.x); acc.y = fmaf(v0, g0.y, acc.y);
        acc.z = fmaf(v0, g0.z, acc.z); acc.w = fmaf(v0, g0.w, acc.w);
        i += 4;
    }
    if (i + e < eend) {
        int   c = cols[i + e];
        float v = vals[i + e];
        float4 g = ((const float4*)(h_gather + (size_t)c * EMB_DIM))[d];
        acc.x = fmaf(v, g.x, acc.x); acc.y = fmaf(v, g.y, acc.y);
        acc.z = fmaf(v, g.z, acc.z); acc.w = fmaf(v, g.w, acc.w);
    }
    acc.x += __shfl_xor(acc.x, 16, 64); acc.y += __shfl_xor(acc.y, 16, 64);
    acc.z += __shfl_xor(acc.z, 16, 64); acc.w += __shfl_xor(acc.w, 16, 64);
    acc.x += __shfl_xor(acc.x, 32, 64); acc.y += __shfl_xor(acc.y, 32, 64);
    acc.z += __shfl_xor(acc.z, 32, 64); acc.w += __shfl_xor(acc.w, 32, 64);
    // acc (= h3 row) now replicated on all 4 groups. Finish expmap on all lanes.
    size_t o = (size_t)row * EMB_DIM + 4 * d;
    float4 a1 = *(const float4*)(h1 + o);
    float4 a2 = *(const float4*)(h2 + o);
    float4 u;
    u.x = (a1.x + a2.x) + acc.x; u.y = (a1.y + a2.y) + acc.y;
    u.z = (a1.z + a2.z) + acc.z; u.w = (a1.w + a2.w) + acc.w;
    float4 x = u;
    if (d == 0) x.x = 0.0f;
    float n2 = group_reduce16(dot4(x, x));
    float xn = fmaxf(sqrtf(n2), MIN_NORM);
    float sh = sinhf(xn);
    float4 rest;
    rest.x = sh * x.x / xn; rest.y = sh * x.y / xn;
    rest.z = sh * x.z / xn; rest.w = sh * x.w / xn;
    float r2 = group_reduce16(dot4(rest, rest));
    float first = sqrtf(1.0f + r2);
    float4 ov = rest;
    if (d == 0) ov.x = first;
    if (e == 0) {
        ((float4*)(h + (size_t)row * EMB_DIM))[d] = ov;
        if (d == 0) nrm2[row] = first * first + r2;
    }
}

// Kernel 5: triplet loss + hard-negative mining. One wave per edge; lane=16e+d.
// 16 p.n dots via reduce-scatter over 16-lane groups (5 shfl total).
__global__ void loss_kernel(const float* __restrict__ h, const float* __restrict__ nrm2,
                            const int* __restrict__ anchor, const int* __restrict__ pos,
                            const int* __restrict__ neg, float* __restrict__ partials) {
    int wib = threadIdx.x >> 6;
    int lane = threadIdx.x & 63;
    int e = lane >> 4, d = lane & 15;
    int i = blockIdx.x * 4 + wib;

    int ia = anchor[i], ip = pos[i];
    float4 a4 = ((const float4*)(h + (size_t)ia * EMB_DIM))[d];
    float4 p4 = ((const float4*)(h + (size_t)ip * EMB_DIM))[d];
    const int* nrow = neg + (size_t)i * NUM_NEG;

    // value b handled by this group: neg index j = b*4 + e
    int   nb[4];
    float s[4];
    #pragma unroll
    for (int b = 0; b < 4; ++b) {
        nb[b] = nrow[b * 4 + e];
        float4 n4 = ((const float4*)(h + (size_t)nb[b] * EMB_DIM))[d];
        s[b] = dot4(p4, n4);
    }
    float dap = dot4(a4, p4);

    // reduce-scatter the 4 values across the 16-lane group:
    // stage xor8: keep 2 values (lo keeps v0,v1; hi keeps v2,v3)
    {
        bool hi = (d & 8) != 0;
        float send0 = hi ? s[0] : s[2];
        float send1 = hi ? s[1] : s[3];
        float r0 = __shfl_xor(send0, 8, 64);
        float r1 = __shfl_xor(send1, 8, 64);
        float k0 = hi ? s[2] : s[0];
        float k1 = hi ? s[3] : s[1];
        s[0] = k0 + r0;
        s[1] = k1 + r1;
    }
    // stage xor4: keep 1 (lo keeps first, hi keeps second)
    float sv;
    {
        bool hi = (d & 4) != 0;
        float send = hi ? s[0] : s[1];
        float r = __shfl_xor(send, 4, 64);
        float k = hi ? s[1] : s[0];
        sv = k + r;
    }
    sv += __shfl_xor(sv, 2, 64);
    sv += __shfl_xor(sv, 1, 64);
    // lane (e,d) holds full <p, n_j> for j = b*4+e, b = ((d>>3)&1)*2 + ((d>>2)&1)
    int nidx_lane = (d & 8) ? ((d & 4) ? nb[3] : nb[2])
                            : ((d & 4) ? nb[1] : nb[0]);
    int j_lane = (((d >> 3) & 1) * 2 + ((d >> 2) & 1)) * 4 + e;

    float np2 = nrm2[ip];
    float bd = nrm2[nidx_lane] + np2 - 2.0f * sv;
    int bj = j_lane;
    // wave-wide argmin with first-occurrence tie-break (duplicate nodes give
    // bitwise-identical d2, so the smaller-j rule matches jnp.argmin exactly)
    #pragma unroll
    for (int off = 32; off > 0; off >>= 1) {
        float od = __shfl_xor(bd, off, 64);
        int   oj = __shfl_xor(bj, off, 64);
        if (od < bd || (od == bd && oj < bj)) { bd = od; bj = oj; }
    }
    int bn = nrow[bj];                                  // uniform broadcast load
    float4 w4 = ((const float4*)(h + (size_t)bn * EMB_DIM))[d];
    float dan = group_reduce16(dot4(a4, w4));
    dap = group_reduce16(dap);

    float loss = 0.0f;
    if (lane == 0) {
        float a0 = a4.x, p0 = p4.x, n0 = w4.x;
        float mink = dap - 2.0f * a0 * p0;
        float th = fmaxf(-mink, 1.0f + EPS);
        float ac = acoshf(th);
        float pos_score = fminf(ac * ac, MAX_SQDIST);
        float score = (1.0f - mink - a0 - p0) / (a0 * p0);
        float wgt = 1.0f / (1.0f + expf(score));        // sigmoid(-score)
        float minkn = dan - 2.0f * a0 * n0;
        float thn = fmaxf(-minkn, 1.0f + EPS);
        float acn = acoshf(thn);
        float neg_score = fminf(acn * acn, MAX_SQDIST);
        loss = fmaxf(pos_score - neg_score + MARGIN * wgt, 0.0f);
    }
    __shared__ float part[4];
    if (lane == 0) part[wib] = loss;
    __syncthreads();
    if (threadIdx.x == 0)
        partials[blockIdx.x] = part[0] + part[1] + part[2] + part[3];
}

// Kernel 6: sum the per-block partials. Single block, 1024 threads.
__global__ void reduce_kernel(const float* __restrict__ partials, float* __restrict__ out) {
    int tid = threadIdx.x;
    float s = 0.0f;
    for (int i = tid; i < LOSS_BLOCKS; i += 1024)
        s += partials[i];
    #pragma unroll
    for (int off = 32; off > 0; off >>= 1)
        s += __shfl_xor(s, off, 64);
    __shared__ float part[16];
    if ((tid & 63) == 0) part[tid >> 6] = s;
    __syncthreads();
    if (tid == 0) {
        float t = 0.0f;
        #pragma unroll
        for (int k = 0; k < 16; ++k) t += part[k];
        out[0] = t;
    }
}

extern "C" void kernel_launch(void* const* d_in, const int* in_sizes, int n_in,
                              void* d_out, int out_size, void* d_ws, size_t ws_size,
                              hipStream_t stream) {
    const float* weight   = (const float*)d_in[0];
    const float* adj_vals = (const float*)d_in[1];
    const int*   adj_row  = (const int*)d_in[2];
    const int*   adj_col  = (const int*)d_in[3];
    const int*   anchor   = (const int*)d_in[4];
    const int*   pos      = (const int*)d_in[5];
    const int*   neg      = (const int*)d_in[6];
    float* out = (float*)d_out;

    const size_t NODE_BYTES = (size_t)N_NODES * EMB_DIM * sizeof(float); // 51.2 MB
    char* ws = (char*)d_ws;
    float* buf0 = (float*)(ws);                    // x_t
    float* buf1 = (float*)(ws + NODE_BYTES);       // h1
    float* buf2 = (float*)(ws + 2 * NODE_BYTES);   // h2
    int*   rp   = (int*)(ws + 3 * NODE_BYTES);                                   // row_ptr
    float* nrm2 = (float*)(ws + 3 * NODE_BYTES + ((size_t)(N_NODES + 2) * 4));   // ||h||^2
    float* hfin = (float*)(ws + 3 * NODE_BYTES + (size_t)(2 * 1024 * 1024));     // final h
    float* partials = (float*)(ws + 4 * NODE_BYTES + (size_t)(2 * 1024 * 1024)); // 64 KB

    int nblk_row  = (N_NODES + 3) / 4;      // wave per row/node, 4 waves/block
    int nblk_node4 = (N_NODES / 4 + 3) / 4; // wave per 4 nodes

    rowptr_kernel<<<(N_NODES + 1 + 255) / 256, 256, 0, stream>>>(adj_row, rp);
    logmap0_kernel<<<nblk_node4, 256, 0, stream>>>(weight, buf0);
    spmm_kernel<<<nblk_row, 256, 0, stream>>>(buf0, buf1, adj_vals, adj_col, rp);
    spmm_kernel<<<nblk_row, 256, 0, stream>>>(buf1, buf2, adj_vals, adj_col, rp);
    spmm_expmap_kernel<<<nblk_row, 256, 0, stream>>>(buf2, buf1, buf2, hfin, nrm2,
                                                     adj_vals, adj_col, rp);
    loss_kernel<<<LOSS_BLOCKS, 256, 0, stream>>>(hfin, nrm2, anchor, pos, neg, partials);
    reduce_kernel<<<1, 1024, 0, stream>>>(partials, out);
}

// Round 5
// 422.734 us; speedup vs baseline: 2.2002x; 1.0163x over previous
//
#include <hip/hip_runtime.h>
#include <hip/hip_bf16.h>
#include <math.h>

#define N_NODES 200000
#define EMB_DIM 64
#define E_ADJ 1600000
#define E_TR 65536
#define NUM_NEG 16
#define EPS 1e-7f
#define MIN_NORM 1e-15f
#define MAX_SQDIST 50.0f
#define MARGIN 0.1f
#define LOSS_BLOCKS (E_TR / 4)   // 16384 blocks, 4 edges (waves) each

typedef float f4 __attribute__((ext_vector_type(4)));

__device__ __forceinline__ float group_reduce16(float v) {
    v += __shfl_xor(v, 8, 64);
    v += __shfl_xor(v, 4, 64);
    v += __shfl_xor(v, 2, 64);
    v += __shfl_xor(v, 1, 64);
    return v;
}

__device__ __forceinline__ float dot4(f4 a, f4 b) {
    return a.x * b.x + a.y * b.y + a.z * b.z + a.w * b.w;
}

// Kernel 0: pack (col<<4, val) -> int2 so the spmm inner loop does one dwordx2
// load per edge and a pure 32-bit gather index.
__global__ void pack_kernel(const int* __restrict__ cols, const float* __restrict__ vals,
                            int2* __restrict__ ev) {
    int i = blockIdx.x * blockDim.x + threadIdx.x;
    if (i < E_ADJ) ev[i] = make_int2(cols[i] << 4, __float_as_int(vals[i]));
}

// Kernel 1: row_ptr[r] = lower_bound(adj_row, r).
__global__ void rowptr_kernel(const int* __restrict__ rows, int* __restrict__ rp) {
    int r = blockIdx.x * blockDim.x + threadIdx.x;
    if (r > N_NODES) return;
    int lo = 0, hi = E_ADJ;
    while (lo < hi) {
        int mid = (lo + hi) >> 1;
        if (rows[mid] < r) lo = mid + 1; else hi = mid;
    }
    rp[r] = lo;
}

// Kernel 2: x_t = logmap0(weight). Wave handles 4 nodes; 16-lane group per node.
__global__ void logmap0_kernel(const float* __restrict__ w, float* __restrict__ out) {
    int wave = (blockIdx.x * blockDim.x + threadIdx.x) >> 6;
    int lane = threadIdx.x & 63;
    int e = lane >> 4, d = lane & 15;
    int node = wave * 4 + e;
    if (node >= N_NODES) return;
    f4 v = ((const f4*)w)[(node << 4) + d];
    f4 y = v;
    if (d == 0) y.x = 0.0f;
    float n2 = group_reduce16(dot4(y, y));
    float ynorm = fmaxf(sqrtf(n2), MIN_NORM);
    float w0 = __shfl(v.x, lane & 48, 64);      // broadcast d==0 lane of group
    float theta = fmaxf(w0, 1.0f + EPS);
    float scale = acoshf(theta) / ynorm;
    ((f4*)out)[(node << 4) + d] = y * scale;
}

// Kernel 3: one SpMM layer. One wave per row; lane=16e+d; 4 edges per gather instr.
__global__ void spmm_kernel(const float* __restrict__ h_in, float* __restrict__ h_out,
                            const int2* __restrict__ ev, const int* __restrict__ rp) {
    int row = (blockIdx.x * blockDim.x + threadIdx.x) >> 6;
    int lane = threadIdx.x & 63;
    int e = lane >> 4, d = lane & 15;
    if (row >= N_NODES) return;
    int s = rp[row], eend = rp[row + 1];
    const f4* H = (const f4*)h_in;
    f4 acc = {0.f, 0.f, 0.f, 0.f};
    int i = s;
    for (; i + 8 <= eend; i += 8) {
        int2 cv0 = ev[i + e];
        int2 cv1 = ev[i + 4 + e];
        f4 g0 = H[cv0.x + d];
        f4 g1 = H[cv1.x + d];
        acc += g0 * __int_as_float(cv0.y);
        acc += g1 * __int_as_float(cv1.y);
    }
    if (i + 4 <= eend) {
        int2 cv = ev[i + e];
        f4 g = H[cv.x + d];
        acc += g * __int_as_float(cv.y);
        i += 4;
    }
    if (i + e < eend) {
        int2 cv = ev[i + e];
        f4 g = H[cv.x + d];
        acc += g * __int_as_float(cv.y);
    }
    // sum across the 4 edge-slot groups (same d, different e)
    acc.x += __shfl_xor(acc.x, 16, 64); acc.y += __shfl_xor(acc.y, 16, 64);
    acc.z += __shfl_xor(acc.z, 16, 64); acc.w += __shfl_xor(acc.w, 16, 64);
    acc.x += __shfl_xor(acc.x, 32, 64); acc.y += __shfl_xor(acc.y, 32, 64);
    acc.z += __shfl_xor(acc.z, 32, 64); acc.w += __shfl_xor(acc.w, 32, 64);
    if (e == 0)
        ((f4*)h_out)[(row << 4) + d] = acc;
}

// Kernel 4: fused layer-3 SpMM + (h1+h2+h3) + expmap0 + proj. Emits h and ||h||^2.
__global__ void spmm_expmap_kernel(const float* __restrict__ h_gather,   // h2 (gather src)
                                   const float* __restrict__ h1, const float* __restrict__ h2,
                                   float* __restrict__ h, float* __restrict__ nrm2,
                                   const int2* __restrict__ ev, const int* __restrict__ rp) {
    int row = (blockIdx.x * blockDim.x + threadIdx.x) >> 6;
    int lane = threadIdx.x & 63;
    int e = lane >> 4, d = lane & 15;
    if (row >= N_NODES) return;
    int s = rp[row], eend = rp[row + 1];
    const f4* H = (const f4*)h_gather;
    f4 acc = {0.f, 0.f, 0.f, 0.f};
    int i = s;
    for (; i + 8 <= eend; i += 8) {
        int2 cv0 = ev[i + e];
        int2 cv1 = ev[i + 4 + e];
        f4 g0 = H[cv0.x + d];
        f4 g1 = H[cv1.x + d];
        acc += g0 * __int_as_float(cv0.y);
        acc += g1 * __int_as_float(cv1.y);
    }
    if (i + 4 <= eend) {
        int2 cv = ev[i + e];
        f4 g = H[cv.x + d];
        acc += g * __int_as_float(cv.y);
        i += 4;
    }
    if (i + e < eend) {
        int2 cv = ev[i + e];
        f4 g = H[cv.x + d];
        acc += g * __int_as_float(cv.y);
    }
    acc.x += __shfl_xor(acc.x, 16, 64); acc.y += __shfl_xor(acc.y, 16, 64);
    acc.z += __shfl_xor(acc.z, 16, 64); acc.w += __shfl_xor(acc.w, 16, 64);
    acc.x += __shfl_xor(acc.x, 32, 64); acc.y += __shfl_xor(acc.y, 32, 64);
    acc.z += __shfl_xor(acc.z, 32, 64); acc.w += __shfl_xor(acc.w, 32, 64);
    // acc (= h3 row) replicated on all 4 e-groups. Finish expmap on all lanes.
    int oi = (row << 4) + d;
    f4 a1 = ((const f4*)h1)[oi];
    f4 a2 = ((const f4*)h2)[oi];
    f4 u = (a1 + a2) + acc;                 // match ref accumulate order
    f4 x = u;
    if (d == 0) x.x = 0.0f;
    float n2 = group_reduce16(dot4(x, x));
    float xn = fmaxf(sqrtf(n2), MIN_NORM);
    float sh = sinhf(xn);
    f4 rest = x * (sh / xn);
    float r2 = group_reduce16(dot4(rest, rest));
    float first = sqrtf(1.0f + r2);
    f4 ov = rest;
    if (d == 0) ov.x = first;
    if (e == 0) {
        ((f4*)h)[oi] = ov;
        if (d == 0) nrm2[row] = first * first + r2;
    }
}

// Kernel 5: triplet loss + hard-negative mining. One wave per edge; lane=16e+d.
__global__ void loss_kernel(const float* __restrict__ h, const float* __restrict__ nrm2,
                            const int* __restrict__ anchor, const int* __restrict__ pos,
                            const int* __restrict__ neg, float* __restrict__ partials) {
    int wib = threadIdx.x >> 6;
    int lane = threadIdx.x & 63;
    int e = lane >> 4, d = lane & 15;
    int i = blockIdx.x * 4 + wib;
    const f4* H = (const f4*)h;

    int ia = anchor[i], ip = pos[i];
    f4 a4 = H[(ia << 4) + d];
    f4 p4 = H[(ip << 4) + d];
    const int* nrow = neg + (size_t)i * NUM_NEG;

    // value b handled by this group: neg index j = b*4 + e
    int   nb[4];
    float s[4];
    #pragma unroll
    for (int b = 0; b < 4; ++b) {
        nb[b] = nrow[b * 4 + e];
        f4 n4 = H[(nb[b] << 4) + d];
        s[b] = dot4(p4, n4);
    }
    float dap = dot4(a4, p4);

    // reduce-scatter the 4 values across the 16-lane group
    {
        bool hi = (d & 8) != 0;
        float send0 = hi ? s[0] : s[2];
        float send1 = hi ? s[1] : s[3];
        float r0 = __shfl_xor(send0, 8, 64);
        float r1 = __shfl_xor(send1, 8, 64);
        float k0 = hi ? s[2] : s[0];
        float k1 = hi ? s[3] : s[1];
        s[0] = k0 + r0;
        s[1] = k1 + r1;
    }
    float sv;
    {
        bool hi = (d & 4) != 0;
        float send = hi ? s[0] : s[1];
        float r = __shfl_xor(send, 4, 64);
        float k = hi ? s[1] : s[0];
        sv = k + r;
    }
    sv += __shfl_xor(sv, 2, 64);
    sv += __shfl_xor(sv, 1, 64);
    // lane (e,d) holds full <p, n_j> for j = b*4+e, b = ((d>>3)&1)*2 + ((d>>2)&1)
    int nidx_lane = (d & 8) ? ((d & 4) ? nb[3] : nb[2])
                            : ((d & 4) ? nb[1] : nb[0]);
    int j_lane = (((d >> 3) & 1) * 2 + ((d >> 2) & 1)) * 4 + e;

    float np2 = nrm2[ip];
    float bd = nrm2[nidx_lane] + np2 - 2.0f * sv;
    int bj = j_lane;
    // wave-wide argmin, first-occurrence tie-break (ties are duplicate nodes ->
    // bitwise-identical d2, so smaller-j rule matches jnp.argmin exactly)
    #pragma unroll
    for (int off = 32; off > 0; off >>= 1) {
        float od = __shfl_xor(bd, off, 64);
        int   oj = __shfl_xor(bj, off, 64);
        if (od < bd || (od == bd && oj < bj)) { bd = od; bj = oj; }
    }
    int bn = nrow[bj];                                  // uniform broadcast load
    f4 w4 = H[(bn << 4) + d];
    float dan = group_reduce16(dot4(a4, w4));
    dap = group_reduce16(dap);

    float loss = 0.0f;
    if (lane == 0) {
        float a0 = a4.x, p0 = p4.x, n0 = w4.x;
        float mink = dap - 2.0f * a0 * p0;
        float th = fmaxf(-mink, 1.0f + EPS);
        float ac = acoshf(th);
        float pos_score = fminf(ac * ac, MAX_SQDIST);
        float score = (1.0f - mink - a0 - p0) / (a0 * p0);
        float wgt = 1.0f / (1.0f + expf(score));        // sigmoid(-score)
        float minkn = dan - 2.0f * a0 * n0;
        float thn = fmaxf(-minkn, 1.0f + EPS);
        float acn = acoshf(thn);
        float neg_score = fminf(acn * acn, MAX_SQDIST);
        loss = fmaxf(pos_score - neg_score + MARGIN * wgt, 0.0f);
    }
    __shared__ float part[4];
    if (lane == 0) part[wib] = loss;
    __syncthreads();
    if (threadIdx.x == 0)
        partials[blockIdx.x] = part[0] + part[1] + part[2] + part[3];
}

// Kernel 6: sum the per-block partials. Single block, 1024 threads.
__global__ void reduce_kernel(const float* __restrict__ partials, float* __restrict__ out) {
    int tid = threadIdx.x;
    float s = 0.0f;
    for (int i = tid; i < LOSS_BLOCKS; i += 1024)
        s += partials[i];
    #pragma unroll
    for (int off = 32; off > 0; off >>= 1)
        s += __shfl_xor(s, off, 64);
    __shared__ float part[16];
    if ((tid & 63) == 0) part[tid >> 6] = s;
    __syncthreads();
    if (tid == 0) {
        float t = 0.0f;
        #pragma unroll
        for (int k = 0; k < 16; ++k) t += part[k];
        out[0] = t;
    }
}

extern "C" void kernel_launch(void* const* d_in, const int* in_sizes, int n_in,
                              void* d_out, int out_size, void* d_ws, size_t ws_size,
                              hipStream_t stream) {
    const float* weight   = (const float*)d_in[0];
    const float* adj_vals = (const float*)d_in[1];
    const int*   adj_row  = (const int*)d_in[2];
    const int*   adj_col  = (const int*)d_in[3];
    const int*   anchor   = (const int*)d_in[4];
    const int*   pos      = (const int*)d_in[5];
    const int*   neg      = (const int*)d_in[6];
    float* out = (float*)d_out;

    const size_t NODE_BYTES = (size_t)N_NODES * EMB_DIM * sizeof(float); // 51.2 MB
    const size_t MB = 1024 * 1024;
    char* ws = (char*)d_ws;
    float* buf0 = (float*)(ws);                    // x_t, later reused as final h
    float* buf1 = (float*)(ws + NODE_BYTES);       // h1
    float* buf2 = (float*)(ws + 2 * NODE_BYTES);   // h2
    int*   rp   = (int*)  (ws + 3 * NODE_BYTES);             // row_ptr  (800 KB)
    float* nrm2 = (float*)(ws + 3 * NODE_BYTES + 1 * MB);    // ||h||^2  (800 KB)
    int2*  ev   = (int2*) (ws + 3 * NODE_BYTES + 2 * MB);    // packed edges (12.8 MB)
    float* partials = (float*)(ws + 3 * NODE_BYTES + 16 * MB); // 64 KB
    float* hfin = buf0;                            // buf0 dead after spmm layer 1

    int nblk_row   = (N_NODES + 3) / 4;      // wave per row, 4 waves/block
    int nblk_node4 = (N_NODES / 4 + 3) / 4;  // wave per 4 nodes

    pack_kernel<<<(E_ADJ + 255) / 256, 256, 0, stream>>>(adj_col, adj_vals, ev);
    rowptr_kernel<<<(N_NODES + 1 + 255) / 256, 256, 0, stream>>>(adj_row, rp);
    logmap0_kernel<<<nblk_node4, 256, 0, stream>>>(weight, buf0);
    spmm_kernel<<<nblk_row, 256, 0, stream>>>(buf0, buf1, ev, rp);
    spmm_kernel<<<nblk_row, 256, 0, stream>>>(buf1, buf2, ev, rp);
    spmm_expmap_kernel<<<nblk_row, 256, 0, stream>>>(buf2, buf1, buf2, hfin, nrm2, ev, rp);
    loss_kernel<<<LOSS_BLOCKS, 256, 0, stream>>>(hfin, nrm2, anchor, pos, neg, partials);
    reduce_kernel<<<1, 1024, 0, stream>>>(partials, out);
}